// Round 1
// baseline (1433.551 us; speedup 1.0000x reference)
//
#include <hip/hip_runtime.h>

// GCN: x'[i] = sum_{e:(s->i)} h[s]*dinv[s]*dinv[i] + h[i]*dinv[i]^2 + b
// deg[i] = indegree(i) + 1 (self loop), dinv = rsqrt(deg)

__global__ void k_deg(const int* __restrict__ dst, float* __restrict__ deg, int E) {
    int e = blockIdx.x * blockDim.x + threadIdx.x;
    if (e < E) atomicAdd(&deg[dst[e]], 1.0f);
}

__global__ void k_dinv(float* __restrict__ deg, int n) {
    int i = blockIdx.x * blockDim.x + threadIdx.x;
    if (i < n) deg[i] = rsqrtf(deg[i] + 1.0f);
}

// H[n,M] = X[n,K] @ W[K,M]; W staged in LDS; one thread per row.
// Same (k,j) sequence across all lanes -> LDS same-address broadcast, no conflicts.
template<int K, int M>
__global__ void k_gemm(const float* __restrict__ X, const float* __restrict__ W,
                       float* __restrict__ H, int n) {
    __shared__ float Ws[K * M];
    for (int i = threadIdx.x; i < K * M; i += blockDim.x) Ws[i] = W[i];
    __syncthreads();
    int r = blockIdx.x * blockDim.x + threadIdx.x;
    if (r >= n) return;
    float acc[M];
#pragma unroll
    for (int j = 0; j < M; j++) acc[j] = 0.f;
    const float* xr = X + (size_t)r * K;
    for (int k = 0; k < K; k += 4) {
        float4 xv = *(const float4*)(xr + k);
#pragma unroll
        for (int j = 0; j < M; j++) {
            acc[j] += xv.x * Ws[(k + 0) * M + j];
            acc[j] += xv.y * Ws[(k + 1) * M + j];
            acc[j] += xv.z * Ws[(k + 2) * M + j];
            acc[j] += xv.w * Ws[(k + 3) * M + j];
        }
    }
    float* hr = H + (size_t)r * M;
#pragma unroll
    for (int j = 0; j < M; j += 4)
        *(float4*)(hr + j) = make_float4(acc[j], acc[j + 1], acc[j + 2], acc[j + 3]);
}

// One F-lane group per edge: gather h[src] row (coalesced), atomic-scatter into agg[dst].
template<int F>
__global__ void k_scatter(const int* __restrict__ src, const int* __restrict__ dst,
                          const float* __restrict__ dinv, const float* __restrict__ H,
                          float* __restrict__ AGG, int E) {
    int t = blockIdx.x * blockDim.x + threadIdx.x;
    int e = t / F;
    int f = t % F;
    if (e >= E) return;
    int s = src[e], d = dst[e];
    float norm = dinv[s] * dinv[d];
    float v = H[s * F + f] * norm;
    atomicAdd(&AGG[d * F + f], v);
}

// AGG <- relu(AGG + H*dinv^2 + b)   (in place; AGG then feeds next GEMM)
template<int F>
__global__ void k_epi(float* __restrict__ AGG, const float* __restrict__ H,
                      const float* __restrict__ dinv, const float* __restrict__ b, int n) {
    int t = blockIdx.x * blockDim.x + threadIdx.x;
    if (t >= n * F) return;
    int r = t / F, f = t % F;
    float di = dinv[r];
    float v = AGG[t] + H[t] * di * di + b[f];
    AGG[t] = fmaxf(v, 0.f);
}

// Fused: v = relu(agg2 + h2*dinv^2 + b2); logits = v @ Wc + bc; log_softmax -> out
__global__ void k_final(const float* __restrict__ AGG2, const float* __restrict__ H2,
                        const float* __restrict__ dinv, const float* __restrict__ b2,
                        const float* __restrict__ Wc, const float* __restrict__ bc,
                        float* __restrict__ out, int n) {
    __shared__ float Wcs[32 * 10];
    __shared__ float b2s[32];
    __shared__ float bcs[10];
    for (int i = threadIdx.x; i < 320; i += blockDim.x) Wcs[i] = Wc[i];
    if (threadIdx.x < 32) b2s[threadIdx.x] = b2[threadIdx.x];
    if (threadIdx.x < 10) bcs[threadIdx.x] = bc[threadIdx.x];
    __syncthreads();
    int r = blockIdx.x * blockDim.x + threadIdx.x;
    if (r >= n) return;
    float di = dinv[r];
    float di2 = di * di;
    const float* a = AGG2 + r * 32;
    const float* h = H2 + r * 32;
    float logits[10];
#pragma unroll
    for (int c = 0; c < 10; c++) logits[c] = bcs[c];
#pragma unroll
    for (int k = 0; k < 32; k += 4) {
        float4 av = *(const float4*)(a + k);
        float4 hv = *(const float4*)(h + k);
        float v0 = fmaxf(av.x + hv.x * di2 + b2s[k + 0], 0.f);
        float v1 = fmaxf(av.y + hv.y * di2 + b2s[k + 1], 0.f);
        float v2 = fmaxf(av.z + hv.z * di2 + b2s[k + 2], 0.f);
        float v3 = fmaxf(av.w + hv.w * di2 + b2s[k + 3], 0.f);
#pragma unroll
        for (int c = 0; c < 10; c++) {
            logits[c] += v0 * Wcs[(k + 0) * 10 + c] + v1 * Wcs[(k + 1) * 10 + c]
                       + v2 * Wcs[(k + 2) * 10 + c] + v3 * Wcs[(k + 3) * 10 + c];
        }
    }
    float m = logits[0];
#pragma unroll
    for (int c = 1; c < 10; c++) m = fmaxf(m, logits[c]);
    float ssum = 0.f;
#pragma unroll
    for (int c = 0; c < 10; c++) ssum += __expf(logits[c] - m);
    float lse = m + __logf(ssum);
    float* o = out + r * 10;
#pragma unroll
    for (int c = 0; c < 10; c++) o[c] = logits[c] - lse;
}

extern "C" void kernel_launch(void* const* d_in, const int* in_sizes, int n_in,
                              void* d_out, int out_size, void* d_ws, size_t ws_size,
                              hipStream_t stream) {
    const float* x  = (const float*)d_in[0];
    const int*   ei = (const int*)d_in[1];
    const float* W1 = (const float*)d_in[2];
    const float* b1 = (const float*)d_in[3];
    const float* W2 = (const float*)d_in[4];
    const float* b2 = (const float*)d_in[5];
    const float* Wc = (const float*)d_in[6];
    const float* bc = (const float*)d_in[7];
    float* out = (float*)d_out;

    const int N = in_sizes[0] / 128;
    const int E = in_sizes[1] / 2;
    const int* src = ei;
    const int* dst = ei + E;

    float* ws = (float*)d_ws;
    size_t off = 0;
    float* dinv = ws + off; off += (size_t)((N + 255) & ~255);
    float* h1   = ws + off; off += (size_t)N * 64;
    float* agg1 = ws + off; off += (size_t)N * 64;
    float* h2   = ws + off; off += (size_t)N * 32;
    float* agg2 = ws + off; off += (size_t)N * 32;

    hipMemsetAsync(dinv, 0, sizeof(float) * (size_t)N, stream);
    hipMemsetAsync(agg1, 0, sizeof(float) * (size_t)N * 64, stream);
    hipMemsetAsync(agg2, 0, sizeof(float) * (size_t)N * 32, stream);

    k_deg<<<(E + 255) / 256, 256, 0, stream>>>(dst, dinv, E);
    k_dinv<<<(N + 255) / 256, 256, 0, stream>>>(dinv, N);

    k_gemm<128, 64><<<(N + 255) / 256, 256, 0, stream>>>(x, W1, h1, N);
    {
        long long tt = (long long)E * 64;
        k_scatter<64><<<(int)((tt + 255) / 256), 256, 0, stream>>>(src, dst, dinv, h1, agg1, E);
    }
    k_epi<64><<<((N * 64) + 255) / 256, 256, 0, stream>>>(agg1, h1, dinv, b1, N);

    k_gemm<64, 32><<<(N + 255) / 256, 256, 0, stream>>>(agg1, W2, h2, N);
    {
        long long tt = (long long)E * 32;
        k_scatter<32><<<(int)((tt + 255) / 256), 256, 0, stream>>>(src, dst, dinv, h2, agg2, E);
    }
    k_final<<<(N + 255) / 256, 256, 0, stream>>>(agg2, h2, dinv, b2, Wc, bc, out, N);
}

// Round 2
// 885.412 us; speedup vs baseline: 1.6191x; 1.6191x over previous
//
#include <hip/hip_runtime.h>

// GCN via CSR-gather (no fp32 atomics):
//   deg[d] = indegree; dinv = rsqrt(deg+1)
//   hs = (X @ W) * dinv[row]                  (gemm epilogue)
//   act[d] = relu(dinv[d]*(sum_{s in N(d)} hs[s] + hs[d]) + b)

#define SCAN_B 256

__global__ void k_deg(const int* __restrict__ dst, int* __restrict__ deg, int E) {
    int e = blockIdx.x * blockDim.x + threadIdx.x;
    if (e < E) atomicAdd(&deg[dst[e]], 1);
}

__global__ void k_blocksum(const int* __restrict__ deg, int* __restrict__ bsum, int n) {
    __shared__ int s[SCAN_B];
    int i = blockIdx.x * SCAN_B + threadIdx.x;
    s[threadIdx.x] = (i < n) ? deg[i] : 0;
    __syncthreads();
    for (int o = SCAN_B / 2; o > 0; o >>= 1) {
        if (threadIdx.x < o) s[threadIdx.x] += s[threadIdx.x + o];
        __syncthreads();
    }
    if (threadIdx.x == 0) bsum[blockIdx.x] = s[0];
}

// single block, exclusive scan of up to 1024 block sums
__global__ void k_scan_bsum(int* __restrict__ bsum, int nb) {
    __shared__ int s[1024];
    int t = threadIdx.x;
    int v = (t < nb) ? bsum[t] : 0;
    s[t] = v;
    __syncthreads();
    for (int o = 1; o < 1024; o <<= 1) {
        int u = (t >= o) ? s[t - o] : 0;
        __syncthreads();
        s[t] += u;
        __syncthreads();
    }
    if (t < nb) bsum[t] = s[t] - v;  // exclusive
}

// rowptr[i] = exclusive scan; degcur becomes the fill cursor; dinv = rsqrt(deg+1)
__global__ void k_scan_final(int* __restrict__ degcur, const int* __restrict__ bsum,
                             int* __restrict__ rowptr, float* __restrict__ dinv,
                             int n, int E) {
    __shared__ int s[SCAN_B];
    int i = blockIdx.x * SCAN_B + threadIdx.x;
    int v = (i < n) ? degcur[i] : 0;
    s[threadIdx.x] = v;
    __syncthreads();
    for (int o = 1; o < SCAN_B; o <<= 1) {
        int u = (threadIdx.x >= o) ? s[threadIdx.x - o] : 0;
        __syncthreads();
        s[threadIdx.x] += u;
        __syncthreads();
    }
    if (i < n) {
        int ex = bsum[blockIdx.x] + s[threadIdx.x] - v;
        rowptr[i] = ex;
        degcur[i] = ex;  // cursor for fill
        dinv[i] = rsqrtf((float)v + 1.0f);
        if (i == n - 1) rowptr[n] = E;
    }
}

__global__ void k_fill(const int* __restrict__ src, const int* __restrict__ dst,
                       int* __restrict__ cursor, int* __restrict__ csr, int E) {
    int e = blockIdx.x * blockDim.x + threadIdx.x;
    if (e < E) {
        int pos = atomicAdd(&cursor[dst[e]], 1);
        csr[pos] = src[e];
    }
}

// H[n,M] = (X[n,K] @ W[K,M]) * dinv[row]; W staged in LDS; one thread per row.
template<int K, int M>
__global__ void k_gemm(const float* __restrict__ X, const float* __restrict__ W,
                       const float* __restrict__ dinv, float* __restrict__ H, int n) {
    __shared__ float Ws[K * M];
    for (int i = threadIdx.x; i < K * M; i += blockDim.x) Ws[i] = W[i];
    __syncthreads();
    int r = blockIdx.x * blockDim.x + threadIdx.x;
    if (r >= n) return;
    float acc[M];
#pragma unroll
    for (int j = 0; j < M; j++) acc[j] = 0.f;
    const float* xr = X + (size_t)r * K;
    for (int k = 0; k < K; k += 4) {
        float4 xv = *(const float4*)(xr + k);
#pragma unroll
        for (int j = 0; j < M; j++) {
            acc[j] += xv.x * Ws[(k + 0) * M + j];
            acc[j] += xv.y * Ws[(k + 1) * M + j];
            acc[j] += xv.z * Ws[(k + 2) * M + j];
            acc[j] += xv.w * Ws[(k + 3) * M + j];
        }
    }
    float di = dinv[r];
    float* hr = H + (size_t)r * M;
#pragma unroll
    for (int j = 0; j < M; j += 4)
        *(float4*)(hr + j) = make_float4(acc[j] * di, acc[j + 1] * di,
                                         acc[j + 2] * di, acc[j + 3] * di);
}

// One wave per node, lane = feature (F=64): act[d] = relu(dinv[d]*(sum hs[s] + hs[d]) + b)
__global__ void k_agg64(const int* __restrict__ rowptr, const int* __restrict__ csr,
                        const float* __restrict__ hs, const float* __restrict__ dinv,
                        const float* __restrict__ b, float* __restrict__ out, int n) {
    int d = (blockIdx.x * blockDim.x + threadIdx.x) >> 6;
    int f = threadIdx.x & 63;
    if (d >= n) return;
    int beg = rowptr[d], end = rowptr[d + 1];
    float acc = hs[(size_t)d * 64 + f];  // self loop
    int j = beg;
    for (; j + 1 < end; j += 2) {
        int s0 = csr[j], s1 = csr[j + 1];
        float v0 = hs[(size_t)s0 * 64 + f];
        float v1 = hs[(size_t)s1 * 64 + f];
        acc += v0;
        acc += v1;
    }
    if (j < end) acc += hs[(size_t)csr[j] * 64 + f];
    float v = acc * dinv[d] + b[f];
    out[(size_t)d * 64 + f] = fmaxf(v, 0.f);
}

// One wave per node, F=32: lanes 0-31 even edges, 32-63 odd edges; combine via shfl.
__global__ void k_agg32(const int* __restrict__ rowptr, const int* __restrict__ csr,
                        const float* __restrict__ hs, const float* __restrict__ dinv,
                        const float* __restrict__ b, float* __restrict__ out, int n) {
    int d = (blockIdx.x * blockDim.x + threadIdx.x) >> 6;
    int f = threadIdx.x & 31;
    int half = (threadIdx.x >> 5) & 1;
    if (d >= n) return;
    int beg = rowptr[d], end = rowptr[d + 1];
    float acc = (half == 0) ? hs[(size_t)d * 32 + f] : 0.f;  // self loop
    int j = beg + half;
    for (; j + 2 < end; j += 4) {
        int s0 = csr[j], s1 = csr[j + 2];
        float v0 = hs[(size_t)s0 * 32 + f];
        float v1 = hs[(size_t)s1 * 32 + f];
        acc += v0;
        acc += v1;
    }
    if (j < end) acc += hs[(size_t)csr[j] * 32 + f];
    acc += __shfl_xor(acc, 32, 64);
    if (half == 0) {
        float v = acc * dinv[d] + b[f];
        out[(size_t)d * 32 + f] = fmaxf(v, 0.f);
    }
}

// logits = act2 @ Wc + bc; log_softmax
__global__ void k_classifier(const float* __restrict__ ACT, const float* __restrict__ Wc,
                             const float* __restrict__ bc, float* __restrict__ out, int n) {
    __shared__ float Wcs[32 * 10];
    __shared__ float bcs[10];
    for (int i = threadIdx.x; i < 320; i += blockDim.x) Wcs[i] = Wc[i];
    if (threadIdx.x < 10) bcs[threadIdx.x] = bc[threadIdx.x];
    __syncthreads();
    int r = blockIdx.x * blockDim.x + threadIdx.x;
    if (r >= n) return;
    const float* a = ACT + (size_t)r * 32;
    float logits[10];
#pragma unroll
    for (int c = 0; c < 10; c++) logits[c] = bcs[c];
#pragma unroll
    for (int k = 0; k < 32; k += 4) {
        float4 av = *(const float4*)(a + k);
#pragma unroll
        for (int c = 0; c < 10; c++) {
            logits[c] += av.x * Wcs[(k + 0) * 10 + c] + av.y * Wcs[(k + 1) * 10 + c]
                       + av.z * Wcs[(k + 2) * 10 + c] + av.w * Wcs[(k + 3) * 10 + c];
        }
    }
    float m = logits[0];
#pragma unroll
    for (int c = 1; c < 10; c++) m = fmaxf(m, logits[c]);
    float ssum = 0.f;
#pragma unroll
    for (int c = 0; c < 10; c++) ssum += __expf(logits[c] - m);
    float lse = m + __logf(ssum);
    float* o = out + (size_t)r * 10;
#pragma unroll
    for (int c = 0; c < 10; c++) o[c] = logits[c] - lse;
}

extern "C" void kernel_launch(void* const* d_in, const int* in_sizes, int n_in,
                              void* d_out, int out_size, void* d_ws, size_t ws_size,
                              hipStream_t stream) {
    const float* x  = (const float*)d_in[0];
    const int*   ei = (const int*)d_in[1];
    const float* W1 = (const float*)d_in[2];
    const float* b1 = (const float*)d_in[3];
    const float* W2 = (const float*)d_in[4];
    const float* b2 = (const float*)d_in[5];
    const float* Wc = (const float*)d_in[6];
    const float* bc = (const float*)d_in[7];
    float* out = (float*)d_out;

    const int N = in_sizes[0] / 128;
    const int E = in_sizes[1] / 2;
    const int* src = ei;
    const int* dst = ei + E;

    const int NB = (N + SCAN_B - 1) / SCAN_B;  // scan blocks (<=1024)

    char* ws = (char*)d_ws;
    size_t off = 0;
    auto alloc = [&](size_t elems) {
        void* p = ws + off;
        off += ((elems * 4 + 1023) & ~(size_t)1023);
        return p;
    };
    float* dinv   = (float*)alloc(N);
    int*   rowptr = (int*)alloc(N + 1);
    int*   degcur = (int*)alloc(N);
    int*   bsum   = (int*)alloc(1024);
    int*   csr    = (int*)alloc(E);
    float* hs1    = (float*)alloc((size_t)N * 64);  // reused as hs2
    float* act1   = (float*)alloc((size_t)N * 64);  // reused as act2
    float* hs2    = hs1;
    float* act2   = act1;

    hipMemsetAsync(degcur, 0, sizeof(int) * (size_t)N, stream);

    // CSR build
    k_deg<<<(E + 255) / 256, 256, 0, stream>>>(dst, degcur, E);
    k_blocksum<<<NB, SCAN_B, 0, stream>>>(degcur, bsum, N);
    k_scan_bsum<<<1, 1024, 0, stream>>>(bsum, NB);
    k_scan_final<<<NB, SCAN_B, 0, stream>>>(degcur, bsum, rowptr, dinv, N, E);
    k_fill<<<(E + 255) / 256, 256, 0, stream>>>(src, dst, degcur, csr, E);

    // Layer 1: 128 -> 64
    k_gemm<128, 64><<<(N + 255) / 256, 256, 0, stream>>>(x, W1, dinv, hs1, N);
    k_agg64<<<(N * 64 + 255) / 256, 256, 0, stream>>>(rowptr, csr, hs1, dinv, b1, act1, N);

    // Layer 2: 64 -> 32
    k_gemm<64, 32><<<(N + 255) / 256, 256, 0, stream>>>(act1, W2, dinv, hs2, N);
    k_agg32<<<(N * 64 + 255) / 256, 256, 0, stream>>>(rowptr, csr, hs2, dinv, b2, act2, N);

    // Classifier + log_softmax
    k_classifier<<<(N + 255) / 256, 256, 0, stream>>>(act2, Wc, bc, out, N);
}

// Round 3
// 808.101 us; speedup vs baseline: 1.7740x; 1.0957x over previous
//
#include <hip/hip_runtime.h>

// GCN via CSR-gather. CSR built with bucketed scatter (dense writes):
//   bucket b = 16-node dst range; bucket base in csr order = rowptr[b*16]
//   binscatter: edge -> packed int (src | dstlo<<17) appended to bucket region
//   bucketsort: per-bucket LDS counting sort -> csr[rowptr[d]+k] = src

#define SCAN_B 256
#define BW_SHIFT 4            // 16 nodes per bucket
#define BW_MASK 15
#define CUR_STRIDE 16         // pad cursors to 64B lines

__global__ void k_deg(const int* __restrict__ dst, int* __restrict__ deg, int E) {
    int e = blockIdx.x * blockDim.x + threadIdx.x;
    if (e < E) atomicAdd(&deg[dst[e]], 1);
}

__global__ void k_blocksum(const int* __restrict__ deg, int* __restrict__ bsum, int n) {
    __shared__ int s[SCAN_B];
    int i = blockIdx.x * SCAN_B + threadIdx.x;
    s[threadIdx.x] = (i < n) ? deg[i] : 0;
    __syncthreads();
    for (int o = SCAN_B / 2; o > 0; o >>= 1) {
        if (threadIdx.x < o) s[threadIdx.x] += s[threadIdx.x + o];
        __syncthreads();
    }
    if (threadIdx.x == 0) bsum[blockIdx.x] = s[0];
}

// single block, exclusive scan of up to 1024 block sums
__global__ void k_scan_bsum(int* __restrict__ bsum, int nb) {
    __shared__ int s[1024];
    int t = threadIdx.x;
    int v = (t < nb) ? bsum[t] : 0;
    s[t] = v;
    __syncthreads();
    for (int o = 1; o < 1024; o <<= 1) {
        int u = (t >= o) ? s[t - o] : 0;
        __syncthreads();
        s[t] += u;
        __syncthreads();
    }
    if (t < nb) bsum[t] = s[t] - v;  // exclusive
}

// rowptr = exclusive scan of deg; dinv = rsqrt(deg+1); bucket cursors = rowptr[b*16]
__global__ void k_scan_final(int* __restrict__ deg, const int* __restrict__ bsum,
                             int* __restrict__ rowptr, float* __restrict__ dinv,
                             int* __restrict__ bcur, int n, int E) {
    __shared__ int s[SCAN_B];
    int i = blockIdx.x * SCAN_B + threadIdx.x;
    int v = (i < n) ? deg[i] : 0;
    s[threadIdx.x] = v;
    __syncthreads();
    for (int o = 1; o < SCAN_B; o <<= 1) {
        int u = (threadIdx.x >= o) ? s[threadIdx.x - o] : 0;
        __syncthreads();
        s[threadIdx.x] += u;
        __syncthreads();
    }
    if (i < n) {
        int ex = bsum[blockIdx.x] + s[threadIdx.x] - v;
        rowptr[i] = ex;
        dinv[i] = rsqrtf((float)v + 1.0f);
        if ((i & BW_MASK) == 0) bcur[(i >> BW_SHIFT) * CUR_STRIDE] = ex;
        if (i == n - 1) rowptr[n] = E;
    }
}

// Append packed (src | dstlo<<17) into the bucket's dense csr-order region.
__global__ void k_binscatter(const int* __restrict__ src, const int* __restrict__ dst,
                             int* __restrict__ bcur, int* __restrict__ binned, int E) {
    int e = blockIdx.x * blockDim.x + threadIdx.x;
    if (e >= E) return;
    int d = dst[e];
    int pos = atomicAdd(&bcur[(d >> BW_SHIFT) * CUR_STRIDE], 1);
    binned[pos] = src[e] | ((d & BW_MASK) << 17);
}

// One block per bucket: counting-sort the bucket's edges into csr (dense region).
__global__ void k_bucketsort(const int* __restrict__ rowptr, const int* __restrict__ binned,
                             int* __restrict__ csr, int n, int nbuck) {
    __shared__ int rp[BW_MASK + 2];
    __shared__ int lcur[BW_MASK + 1];
    int b = blockIdx.x;
    int lo = b << BW_SHIFT;
    int width = min(n - lo, BW_MASK + 1);
    if (threadIdx.x <= width) rp[threadIdx.x] = rowptr[lo + threadIdx.x];
    if (threadIdx.x <= BW_MASK) lcur[threadIdx.x] = 0;
    __syncthreads();
    int beg = rp[0], end = rp[width];
    for (int i = beg + threadIdx.x; i < end; i += blockDim.x) {
        int v = binned[i];
        int ln = (v >> 17) & BW_MASK;
        int k = atomicAdd(&lcur[ln], 1);
        csr[rp[ln] + k] = v & 0x1FFFF;
    }
}

// H[n,M] = (X[n,K] @ W[K,M]) * dinv[row]; W staged in LDS; one thread per row.
template<int K, int M>
__global__ void k_gemm(const float* __restrict__ X, const float* __restrict__ W,
                       const float* __restrict__ dinv, float* __restrict__ H, int n) {
    __shared__ float Ws[K * M];
    for (int i = threadIdx.x; i < K * M; i += blockDim.x) Ws[i] = W[i];
    __syncthreads();
    int r = blockIdx.x * blockDim.x + threadIdx.x;
    if (r >= n) return;
    float acc[M];
#pragma unroll
    for (int j = 0; j < M; j++) acc[j] = 0.f;
    const float* xr = X + (size_t)r * K;
    for (int k = 0; k < K; k += 4) {
        float4 xv = *(const float4*)(xr + k);
#pragma unroll
        for (int j = 0; j < M; j++) {
            acc[j] += xv.x * Ws[(k + 0) * M + j];
            acc[j] += xv.y * Ws[(k + 1) * M + j];
            acc[j] += xv.z * Ws[(k + 2) * M + j];
            acc[j] += xv.w * Ws[(k + 3) * M + j];
        }
    }
    float di = dinv[r];
    float* hr = H + (size_t)r * M;
#pragma unroll
    for (int j = 0; j < M; j += 4)
        *(float4*)(hr + j) = make_float4(acc[j] * di, acc[j + 1] * di,
                                         acc[j + 2] * di, acc[j + 3] * di);
}

// One wave per node, lane = feature (F=64): act[d] = relu(dinv[d]*(sum hs[s] + hs[d]) + b)
__global__ void k_agg64(const int* __restrict__ rowptr, const int* __restrict__ csr,
                        const float* __restrict__ hs, const float* __restrict__ dinv,
                        const float* __restrict__ b, float* __restrict__ out, int n) {
    int d = (blockIdx.x * blockDim.x + threadIdx.x) >> 6;
    int f = threadIdx.x & 63;
    if (d >= n) return;
    int beg = rowptr[d], end = rowptr[d + 1];
    float acc = hs[(size_t)d * 64 + f];  // self loop
    int j = beg;
    for (; j + 1 < end; j += 2) {
        int s0 = csr[j], s1 = csr[j + 1];
        float v0 = hs[(size_t)s0 * 64 + f];
        float v1 = hs[(size_t)s1 * 64 + f];
        acc += v0;
        acc += v1;
    }
    if (j < end) acc += hs[(size_t)csr[j] * 64 + f];
    float v = acc * dinv[d] + b[f];
    out[(size_t)d * 64 + f] = fmaxf(v, 0.f);
}

// One wave per node, F=32: lanes 0-31 even edges, 32-63 odd edges; combine via shfl.
__global__ void k_agg32(const int* __restrict__ rowptr, const int* __restrict__ csr,
                        const float* __restrict__ hs, const float* __restrict__ dinv,
                        const float* __restrict__ b, float* __restrict__ out, int n) {
    int d = (blockIdx.x * blockDim.x + threadIdx.x) >> 6;
    int f = threadIdx.x & 31;
    int half = (threadIdx.x >> 5) & 1;
    if (d >= n) return;
    int beg = rowptr[d], end = rowptr[d + 1];
    float acc = (half == 0) ? hs[(size_t)d * 32 + f] : 0.f;  // self loop
    int j = beg + half;
    for (; j + 2 < end; j += 4) {
        int s0 = csr[j], s1 = csr[j + 2];
        float v0 = hs[(size_t)s0 * 32 + f];
        float v1 = hs[(size_t)s1 * 32 + f];
        acc += v0;
        acc += v1;
    }
    if (j < end) acc += hs[(size_t)csr[j] * 32 + f];
    acc += __shfl_xor(acc, 32, 64);
    if (half == 0) {
        float v = acc * dinv[d] + b[f];
        out[(size_t)d * 32 + f] = fmaxf(v, 0.f);
    }
}

// logits = act2 @ Wc + bc; log_softmax
__global__ void k_classifier(const float* __restrict__ ACT, const float* __restrict__ Wc,
                             const float* __restrict__ bc, float* __restrict__ out, int n) {
    __shared__ float Wcs[32 * 10];
    __shared__ float bcs[10];
    for (int i = threadIdx.x; i < 320; i += blockDim.x) Wcs[i] = Wc[i];
    if (threadIdx.x < 10) bcs[threadIdx.x] = bc[threadIdx.x];
    __syncthreads();
    int r = blockIdx.x * blockDim.x + threadIdx.x;
    if (r >= n) return;
    const float* a = ACT + (size_t)r * 32;
    float logits[10];
#pragma unroll
    for (int c = 0; c < 10; c++) logits[c] = bcs[c];
#pragma unroll
    for (int k = 0; k < 32; k += 4) {
        float4 av = *(const float4*)(a + k);
#pragma unroll
        for (int c = 0; c < 10; c++) {
            logits[c] += av.x * Wcs[(k + 0) * 10 + c] + av.y * Wcs[(k + 1) * 10 + c]
                       + av.z * Wcs[(k + 2) * 10 + c] + av.w * Wcs[(k + 3) * 10 + c];
        }
    }
    float m = logits[0];
#pragma unroll
    for (int c = 1; c < 10; c++) m = fmaxf(m, logits[c]);
    float ssum = 0.f;
#pragma unroll
    for (int c = 0; c < 10; c++) ssum += __expf(logits[c] - m);
    float lse = m + __logf(ssum);
    float* o = out + (size_t)r * 10;
#pragma unroll
    for (int c = 0; c < 10; c++) o[c] = logits[c] - lse;
}

extern "C" void kernel_launch(void* const* d_in, const int* in_sizes, int n_in,
                              void* d_out, int out_size, void* d_ws, size_t ws_size,
                              hipStream_t stream) {
    const float* x  = (const float*)d_in[0];
    const int*   ei = (const int*)d_in[1];
    const float* W1 = (const float*)d_in[2];
    const float* b1 = (const float*)d_in[3];
    const float* W2 = (const float*)d_in[4];
    const float* b2 = (const float*)d_in[5];
    const float* Wc = (const float*)d_in[6];
    const float* bc = (const float*)d_in[7];
    float* out = (float*)d_out;

    const int N = in_sizes[0] / 128;
    const int E = in_sizes[1] / 2;
    const int* src = ei;
    const int* dst = ei + E;

    const int NB = (N + SCAN_B - 1) / SCAN_B;          // scan blocks (<=1024)
    const int NBUCK = (N + BW_MASK) >> BW_SHIFT;       // 16-node buckets

    char* ws = (char*)d_ws;
    size_t off = 0;
    auto alloc = [&](size_t elems) {
        void* p = ws + off;
        off += ((elems * 4 + 1023) & ~(size_t)1023);
        return p;
    };
    float* dinv   = (float*)alloc(N);
    int*   rowptr = (int*)alloc(N + 1);
    int*   degcur = (int*)alloc(N);
    int*   bsum   = (int*)alloc(1024);
    int*   csr    = (int*)alloc(E);
    float* hs1    = (float*)alloc((size_t)N * 64);  // reused as hs2; binned aliases here
    float* act1   = (float*)alloc((size_t)N * 64);  // reused as act2; bcur aliases here
    float* hs2    = hs1;
    float* act2   = act1;
    int*   binned = (int*)hs1;   // E ints, only live before k_gemm writes hs1
    int*   bcur   = (int*)act1;  // NBUCK*CUR_STRIDE ints, only live before act1

    hipMemsetAsync(degcur, 0, sizeof(int) * (size_t)N, stream);

    // CSR build
    k_deg<<<(E + 255) / 256, 256, 0, stream>>>(dst, degcur, E);
    k_blocksum<<<NB, SCAN_B, 0, stream>>>(degcur, bsum, N);
    k_scan_bsum<<<1, 1024, 0, stream>>>(bsum, NB);
    k_scan_final<<<NB, SCAN_B, 0, stream>>>(degcur, bsum, rowptr, dinv, bcur, N, E);
    k_binscatter<<<(E + 255) / 256, 256, 0, stream>>>(src, dst, bcur, binned, E);
    k_bucketsort<<<NBUCK, 256, 0, stream>>>(rowptr, binned, csr, N, NBUCK);

    // Layer 1: 128 -> 64
    k_gemm<128, 64><<<(N + 255) / 256, 256, 0, stream>>>(x, W1, dinv, hs1, N);
    k_agg64<<<(N * 64 + 255) / 256, 256, 0, stream>>>(rowptr, csr, hs1, dinv, b1, act1, N);

    // Layer 2: 64 -> 32
    k_gemm<64, 32><<<(N + 255) / 256, 256, 0, stream>>>(act1, W2, dinv, hs2, N);
    k_agg32<<<(N * 64 + 255) / 256, 256, 0, stream>>>(rowptr, csr, hs2, dinv, b2, act2, N);

    // Classifier + log_softmax
    k_classifier<<<(N + 255) / 256, 256, 0, stream>>>(act2, Wc, bc, out, N);
}